// Round 1
// baseline (582.101 us; speedup 1.0000x reference)
//
#include <hip/hip_runtime.h>

#define FDIM 64

// ---------------- degree / normalization ----------------

__global__ void k_init_deg(float* deg, int n) {
    int i = blockIdx.x * blockDim.x + threadIdx.x;
    if (i < n) deg[i] = 1.0f;   // self-loop
}

__global__ void k_count(const int* __restrict__ ei, float* deg, int nE) {
    int e = blockIdx.x * blockDim.x + threadIdx.x;
    if (e < nE) {
        int d = ei[nE + e];     // dst row of edge_index
        atomicAdd(&deg[d], 1.0f);
    }
}

__global__ void k_rsqrt(float* deg, int n) {
    int i = blockIdx.x * blockDim.x + threadIdx.x;
    if (i < n) deg[i] = rsqrtf(deg[i]);   // in-place: deg -> dis
}

// ---------------- GEMM: H = X @ W  (K = 64, Fout = 64) ----------------
// 64 rows per block, 256 threads, each thread computes a 4x4 output tile.

__global__ __launch_bounds__(256) void k_gemm64(const float* __restrict__ X,
                                                const float* __restrict__ W,
                                                float* __restrict__ H) {
    __shared__ float Ws[64 * 64];     // [k][f]
    __shared__ float XsT[64 * 68];    // [k][r], stride 68 (16B-aligned rows, bank-spread)

    const int tid  = threadIdx.x;          // 0..255
    const int row0 = blockIdx.x * 64;

    for (int i = tid; i < 4096; i += 256) Ws[i] = W[i];
    for (int i = tid; i < 4096; i += 256) {
        int r = i >> 6, k = i & 63;
        XsT[k * 68 + r] = X[(row0 + r) * FDIM + k];
    }
    __syncthreads();

    const int tx = tid & 15;   // feature quad: f = tx*4 .. tx*4+3
    const int ty = tid >> 4;   // row quad:     r = ty*4 .. ty*4+3

    float4 acc0 = {0,0,0,0}, acc1 = {0,0,0,0}, acc2 = {0,0,0,0}, acc3 = {0,0,0,0};

    #pragma unroll
    for (int k = 0; k < 64; ++k) {
        float4 wv = *(const float4*)&Ws[k * 64 + tx * 4];
        float4 xv = *(const float4*)&XsT[k * 68 + ty * 4];
        acc0.x = fmaf(xv.x, wv.x, acc0.x); acc0.y = fmaf(xv.x, wv.y, acc0.y);
        acc0.z = fmaf(xv.x, wv.z, acc0.z); acc0.w = fmaf(xv.x, wv.w, acc0.w);
        acc1.x = fmaf(xv.y, wv.x, acc1.x); acc1.y = fmaf(xv.y, wv.y, acc1.y);
        acc1.z = fmaf(xv.y, wv.z, acc1.z); acc1.w = fmaf(xv.y, wv.w, acc1.w);
        acc2.x = fmaf(xv.z, wv.x, acc2.x); acc2.y = fmaf(xv.z, wv.y, acc2.y);
        acc2.z = fmaf(xv.z, wv.z, acc2.z); acc2.w = fmaf(xv.z, wv.w, acc2.w);
        acc3.x = fmaf(xv.w, wv.x, acc3.x); acc3.y = fmaf(xv.w, wv.y, acc3.y);
        acc3.z = fmaf(xv.w, wv.z, acc3.z); acc3.w = fmaf(xv.w, wv.w, acc3.w);
    }

    float4* H4 = (float4*)H;
    const int fq = tx;  // float4 index within row
    H4[(row0 + ty * 4 + 0) * 16 + fq] = acc0;
    H4[(row0 + ty * 4 + 1) * 16 + fq] = acc1;
    H4[(row0 + ty * 4 + 2) * 16 + fq] = acc2;
    H4[(row0 + ty * 4 + 3) * 16 + fq] = acc3;
}

// ---------------- edge scatter: agg[dst] += h[src] * dis[src]*dis[dst] ----------------
// blockDim = (64, 4): lane = feature, y = edge-in-block.

__global__ __launch_bounds__(256) void k_scatter(const float* __restrict__ H,
                                                 const float* __restrict__ dis,
                                                 const int* __restrict__ ei,
                                                 float* __restrict__ agg, int nE) {
    int e = blockIdx.x * 4 + threadIdx.y;
    if (e >= nE) return;
    int f = threadIdx.x;
    int s = ei[e];
    int d = ei[nE + e];
    float norm = dis[s] * dis[d];
    float v = H[s * FDIM + f] * norm;
    atomicAdd(&agg[d * FDIM + f], v);
}

// ---------------- finalize: out = relu(agg + h*dis^2 + b) ----------------

__global__ void k_finalize(const float* __restrict__ agg,
                           const float* __restrict__ H,
                           const float* __restrict__ dis,
                           const float* __restrict__ b,
                           float* __restrict__ out, int n4) {
    int i = blockIdx.x * blockDim.x + threadIdx.x;   // over N*16 float4s
    if (i >= n4) return;
    int row = i >> 4;
    int fq  = i & 15;
    float ds = dis[row];
    float d2 = ds * ds;
    float4 a  = ((const float4*)agg)[i];
    float4 h  = ((const float4*)H)[i];
    float4 bb = ((const float4*)b)[fq];
    float4 r;
    r.x = fmaxf(fmaf(h.x, d2, a.x) + bb.x, 0.f);
    r.y = fmaxf(fmaf(h.y, d2, a.y) + bb.y, 0.f);
    r.z = fmaxf(fmaf(h.z, d2, a.z) + bb.z, 0.f);
    r.w = fmaxf(fmaf(h.w, d2, a.w) + bb.w, 0.f);
    ((float4*)out)[i] = r;
}

// ---------------- launch ----------------

extern "C" void kernel_launch(void* const* d_in, const int* in_sizes, int n_in,
                              void* d_out, int out_size, void* d_ws, size_t ws_size,
                              hipStream_t stream) {
    const float* x  = (const float*)d_in[0];
    const int*   ei = (const int*)d_in[1];
    const float* W1 = (const float*)d_in[2];
    const float* b1 = (const float*)d_in[3];
    const float* W2 = (const float*)d_in[4];
    const float* b2 = (const float*)d_in[5];

    const int N  = in_sizes[0] / FDIM;       // 65536
    const int E  = in_sizes[1] / 2;          // 1048576
    const size_t featBytes = (size_t)N * FDIM * sizeof(float);  // 16 MB

    float* deg = (float*)d_ws;                       // N floats (becomes dis)
    float* A   = (float*)((char*)d_ws + ((size_t)N * sizeof(float) + 255 & ~(size_t)255)); // 16 MB
    float* out = (float*)d_out;                      // also used as 16 MB scratch

    const int n4 = N * (FDIM / 4);

    // normalization (shared by both layers)
    k_init_deg<<<(N + 255) / 256, 256, 0, stream>>>(deg, N);
    k_count   <<<(E + 255) / 256, 256, 0, stream>>>(ei, deg, E);
    k_rsqrt   <<<(N + 255) / 256, 256, 0, stream>>>(deg, N);

    // ---- layer 1 ----
    k_gemm64<<<N / 64, 256, 0, stream>>>(x, W1, A);            // A = h1
    hipMemsetAsync(out, 0, featBytes, stream);                 // out = agg1 scratch
    k_scatter<<<(E + 3) / 4, dim3(64, 4), 0, stream>>>(A, deg, ei, out, E);
    k_finalize<<<(n4 + 255) / 256, 256, 0, stream>>>(out, A, deg, b1, A, n4);  // A = y1

    // ---- layer 2 ----
    k_gemm64<<<N / 64, 256, 0, stream>>>(A, W2, out);          // out = h2
    hipMemsetAsync(A, 0, featBytes, stream);                   // A = agg2
    k_scatter<<<(E + 3) / 4, dim3(64, 4), 0, stream>>>(out, deg, ei, A, E);
    k_finalize<<<(n4 + 255) / 256, 256, 0, stream>>>(A, out, deg, b2, out, n4); // final
}

// Round 2
// 261.671 us; speedup vs baseline: 2.2246x; 2.2246x over previous
//
#include <hip/hip_runtime.h>

#define FDIM 64

// ================= CSR build =================

__global__ void k_count_int(const int* __restrict__ ei, int* __restrict__ cnt, int nE) {
    int e = blockIdx.x * blockDim.x + threadIdx.x;
    if (e < nE) atomicAdd(&cnt[nE + e - nE + 0 * e + cnt != cnt ? 0 : ei[nE + e]], 1); // placeholder avoided below
}

// (real one — keep it simple)
__global__ void k_count(const int* __restrict__ ei, int* __restrict__ cnt, int nE) {
    int e = blockIdx.x * blockDim.x + threadIdx.x;
    if (e < nE) atomicAdd(&cnt[ei[nE + e]], 1);
}

__global__ void k_deg_dis(const int* __restrict__ cnt, float* __restrict__ dis, int n) {
    int i = blockIdx.x * blockDim.x + threadIdx.x;
    if (i < n) dis[i] = rsqrtf((float)cnt[i] + 1.0f);   // +1 self-loop
}

// exclusive scan of 65536 = 256 x 256
__global__ void k_scan1(const int* __restrict__ cnt, int* __restrict__ rowStart,
                        int* __restrict__ blockSums) {
    __shared__ int s[256];
    int tid = threadIdx.x;
    int i = blockIdx.x * 256 + tid;
    int v = cnt[i];
    s[tid] = v;
    __syncthreads();
    #pragma unroll
    for (int off = 1; off < 256; off <<= 1) {
        int t = (tid >= off) ? s[tid - off] : 0;
        __syncthreads();
        s[tid] += t;
        __syncthreads();
    }
    rowStart[i] = s[tid] - v;                 // exclusive
    if (tid == 255) blockSums[blockIdx.x] = s[255];
}

__global__ void k_scan2(int* __restrict__ blockSums) {
    __shared__ int s[256];
    int tid = threadIdx.x;
    int v = blockSums[tid];
    s[tid] = v;
    __syncthreads();
    #pragma unroll
    for (int off = 1; off < 256; off <<= 1) {
        int t = (tid >= off) ? s[tid - off] : 0;
        __syncthreads();
        s[tid] += t;
        __syncthreads();
    }
    blockSums[tid] = s[tid] - v;              // exclusive block offsets
}

__global__ void k_scan3(int* __restrict__ rowStart, const int* __restrict__ blockSums,
                        int* __restrict__ cursor, int n, int nE) {
    int i = blockIdx.x * 256 + threadIdx.x;
    int r = rowStart[i] + blockSums[i >> 8];
    rowStart[i] = r;
    cursor[i] = r;
    if (i == 0) rowStart[n] = nE;
}

__global__ void k_bucket(const int* __restrict__ ei, int* __restrict__ cursor,
                         int* __restrict__ sortedSrc, int nE) {
    int e = blockIdx.x * blockDim.x + threadIdx.x;
    if (e < nE) {
        int s = ei[e];
        int d = ei[nE + e];
        int pos = atomicAdd(&cursor[d], 1);
        sortedSrc[pos] = s;
    }
}

// ================= GEMM: HS = (X @ W) * dis[row] =================
// 64 rows/block, 256 threads, 4x4 outputs/thread.

__global__ __launch_bounds__(256) void k_gemm64s(const float* __restrict__ X,
                                                 const float* __restrict__ W,
                                                 const float* __restrict__ dis,
                                                 float* __restrict__ H) {
    __shared__ float Ws[64 * 64];     // [k][f]
    __shared__ float XsT[64 * 68];    // [k][r]

    const int tid  = threadIdx.x;
    const int row0 = blockIdx.x * 64;

    for (int i = tid; i < 4096; i += 256) Ws[i] = W[i];
    for (int i = tid; i < 4096; i += 256) {
        int r = i >> 6, k = i & 63;
        XsT[k * 68 + r] = X[(row0 + r) * FDIM + k];
    }
    __syncthreads();

    const int tx = tid & 15;   // feature quad
    const int ty = tid >> 4;   // row quad

    float4 acc0 = {0,0,0,0}, acc1 = {0,0,0,0}, acc2 = {0,0,0,0}, acc3 = {0,0,0,0};

    #pragma unroll
    for (int k = 0; k < 64; ++k) {
        float4 wv = *(const float4*)&Ws[k * 64 + tx * 4];
        float4 xv = *(const float4*)&XsT[k * 68 + ty * 4];
        acc0.x = fmaf(xv.x, wv.x, acc0.x); acc0.y = fmaf(xv.x, wv.y, acc0.y);
        acc0.z = fmaf(xv.x, wv.z, acc0.z); acc0.w = fmaf(xv.x, wv.w, acc0.w);
        acc1.x = fmaf(xv.y, wv.x, acc1.x); acc1.y = fmaf(xv.y, wv.y, acc1.y);
        acc1.z = fmaf(xv.y, wv.z, acc1.z); acc1.w = fmaf(xv.y, wv.w, acc1.w);
        acc2.x = fmaf(xv.z, wv.x, acc2.x); acc2.y = fmaf(xv.z, wv.y, acc2.y);
        acc2.z = fmaf(xv.z, wv.z, acc2.z); acc2.w = fmaf(xv.z, wv.w, acc2.w);
        acc3.x = fmaf(xv.w, wv.x, acc3.x); acc3.y = fmaf(xv.w, wv.y, acc3.y);
        acc3.z = fmaf(xv.w, wv.z, acc3.z); acc3.w = fmaf(xv.w, wv.w, acc3.w);
    }

    float d0 = dis[row0 + ty * 4 + 0];
    float d1 = dis[row0 + ty * 4 + 1];
    float d2 = dis[row0 + ty * 4 + 2];
    float d3 = dis[row0 + ty * 4 + 3];
    acc0.x *= d0; acc0.y *= d0; acc0.z *= d0; acc0.w *= d0;
    acc1.x *= d1; acc1.y *= d1; acc1.z *= d1; acc1.w *= d1;
    acc2.x *= d2; acc2.y *= d2; acc2.z *= d2; acc2.w *= d2;
    acc3.x *= d3; acc3.y *= d3; acc3.z *= d3; acc3.w *= d3;

    float4* H4 = (float4*)H;
    H4[(row0 + ty * 4 + 0) * 16 + tx] = acc0;
    H4[(row0 + ty * 4 + 1) * 16 + tx] = acc1;
    H4[(row0 + ty * 4 + 2) * 16 + tx] = acc2;
    H4[(row0 + ty * 4 + 3) * 16 + tx] = acc3;
}

// ================= aggregation: out = relu(dis[d]*(sum_{s in N(d)} HS[s] + HS[d]) + b) ====
// 1 wave per row; lane = eq*16+fq: eq strides edges (x4 ILP), fq = float4 of features.

__global__ __launch_bounds__(256) void k_agg(const float* __restrict__ HS,
                                             const float* __restrict__ dis,
                                             const int* __restrict__ rowStart,
                                             const int* __restrict__ esrc,
                                             const float* __restrict__ bias,
                                             float* __restrict__ out) {
    const int lane = threadIdx.x & 63;
    const int row  = blockIdx.x * 4 + (threadIdx.x >> 6);
    const int fq   = lane & 15;
    const int eq   = lane >> 4;

    const int start = rowStart[row];
    const int end   = rowStart[row + 1];

    const float4* H4 = (const float4*)HS;
    float4 acc = {0.f, 0.f, 0.f, 0.f};

    for (int k = start + eq; k < end; k += 4) {
        int s = esrc[k];
        float4 v = H4[s * 16 + fq];
        acc.x += v.x; acc.y += v.y; acc.z += v.z; acc.w += v.w;
    }

    // butterfly-reduce across the 4 eq groups (lanes xor 16, 32)
    acc.x += __shfl_xor(acc.x, 16, 64); acc.y += __shfl_xor(acc.y, 16, 64);
    acc.z += __shfl_xor(acc.z, 16, 64); acc.w += __shfl_xor(acc.w, 16, 64);
    acc.x += __shfl_xor(acc.x, 32, 64); acc.y += __shfl_xor(acc.y, 32, 64);
    acc.z += __shfl_xor(acc.z, 32, 64); acc.w += __shfl_xor(acc.w, 32, 64);

    float4 self = H4[row * 16 + fq];
    float  ds   = dis[row];
    float4 bb   = ((const float4*)bias)[fq];

    float4 r;
    r.x = fmaxf(fmaf(acc.x + self.x, ds, bb.x), 0.f);
    r.y = fmaxf(fmaf(acc.y + self.y, ds, bb.y), 0.f);
    r.z = fmaxf(fmaf(acc.z + self.z, ds, bb.z), 0.f);
    r.w = fmaxf(fmaf(acc.w + self.w, ds, bb.w), 0.f);

    if (eq == 0) ((float4*)out)[row * 16 + fq] = r;
}

// ================= launch =================

extern "C" void kernel_launch(void* const* d_in, const int* in_sizes, int n_in,
                              void* d_out, int out_size, void* d_ws, size_t ws_size,
                              hipStream_t stream) {
    const float* x  = (const float*)d_in[0];
    const int*   ei = (const int*)d_in[1];
    const float* W1 = (const float*)d_in[2];
    const float* b1 = (const float*)d_in[3];
    const float* W2 = (const float*)d_in[4];
    const float* b2 = (const float*)d_in[5];

    const int N = in_sizes[0] / FDIM;    // 65536
    const int E = in_sizes[1] / 2;       // 1048576

    char* ws = (char*)d_ws;
    float* dis       = (float*)(ws);                         // N floats
    int*   rowStart  = (int*)  (ws + 262400);                // N+1 ints
    int*   cnt       = (int*)  (ws + 525056);                // N ints (also cursor)
    int*   blockSums = (int*)  (ws + 787456);                // 256 ints
    int*   sortedSrc = (int*)  (ws + 788480);                // E ints
    float* A         = (float*)(ws + 788480 + 4194304);      // N*64 floats (16 MB)
    float* B         = (float*)d_out;                        // 16 MB scratch / final out

    // ---- CSR build (shared by both layers) ----
    hipMemsetAsync(cnt, 0, (size_t)N * sizeof(int), stream);
    k_count  <<<E / 256, 256, 0, stream>>>(ei, cnt, E);
    k_deg_dis<<<N / 256, 256, 0, stream>>>(cnt, dis, N);
    k_scan1  <<<256, 256, 0, stream>>>(cnt, rowStart, blockSums);
    k_scan2  <<<1, 256, 0, stream>>>(blockSums);
    k_scan3  <<<256, 256, 0, stream>>>(rowStart, blockSums, cnt /*cursor*/, N, E);
    k_bucket <<<E / 256, 256, 0, stream>>>(ei, cnt /*cursor*/, sortedSrc, E);

    // ---- layer 1 ----
    k_gemm64s<<<N / 64, 256, 0, stream>>>(x, W1, dis, A);
    k_agg    <<<N / 4, 256, 0, stream>>>(A, dis, rowStart, sortedSrc, b1, B);

    // ---- layer 2 ----
    k_gemm64s<<<N / 64, 256, 0, stream>>>(B, W2, dis, A);
    k_agg    <<<N / 4, 256, 0, stream>>>(A, dis, rowStart, sortedSrc, b2, (float*)d_out);
}

// Round 3
// 177.893 us; speedup vs baseline: 3.2722x; 1.4709x over previous
//
#include <hip/hip_runtime.h>

#define FDIM 64

// ============== CSR build: hierarchical counting sort by dst ==============
// Stage 1: 256-bin histogram over dst>>8.

__global__ __launch_bounds__(256) void k_hist(const int* __restrict__ ei,
                                              int* __restrict__ hist, int nE) {
    __shared__ int lh[256];
    int t = threadIdx.x;
    lh[t] = 0;
    __syncthreads();
    int base = blockIdx.x * 8192;
    #pragma unroll 4
    for (int i = 0; i < 32; ++i) {
        int e = base + i * 256 + t;
        if (e < nE) atomicAdd(&lh[ei[nE + e] >> 8], 1);
    }
    __syncthreads();
    if (lh[t]) atomicAdd(&hist[t], lh[t]);
}

// Stage 2: exclusive scan of the 256 bins -> bucketBase, init cursors.

__global__ void k_scan256(const int* __restrict__ hist, int* __restrict__ bbase,
                          int* __restrict__ cursor, int nE) {
    __shared__ int s[256];
    int t = threadIdx.x;
    int v = hist[t];
    s[t] = v;
    __syncthreads();
    #pragma unroll
    for (int off = 1; off < 256; off <<= 1) {
        int u = (t >= off) ? s[t - off] : 0;
        __syncthreads();
        s[t] += u;
        __syncthreads();
    }
    bbase[t]  = s[t] - v;
    cursor[t] = s[t] - v;
    if (t == 255) bbase[256] = nE;
}

// Stage 3: coarse scatter into bucket-sorted order, packed (src<<8)|(dst&255).
// Per-block LDS histogram + one reservation atomic per (block,bin) ->
// global writes are dense runs, no fine-grained cross-XCD line ping-pong.

__global__ __launch_bounds__(256) void k_coarse(const int* __restrict__ ei,
                                                int* __restrict__ cursor,
                                                int* __restrict__ packed, int nE) {
    __shared__ int lh[256], gb[256], lc[256];
    int t = threadIdx.x;
    lh[t] = 0; lc[t] = 0;
    __syncthreads();
    int base = blockIdx.x * 8192;
    int bins[32], vals[32];
    #pragma unroll 4
    for (int i = 0; i < 32; ++i) {
        int e = base + i * 256 + t;
        if (e < nE) {
            int s = ei[e];
            int d = ei[nE + e];
            bins[i] = d >> 8;
            vals[i] = (s << 8) | (d & 255);
            atomicAdd(&lh[bins[i]], 1);
        } else {
            bins[i] = -1;
        }
    }
    __syncthreads();
    gb[t] = atomicAdd(&cursor[t], lh[t]);   // reserve this block's run in bin t
    __syncthreads();
    #pragma unroll 4
    for (int i = 0; i < 32; ++i) {
        int b = bins[i];
        if (b >= 0) {
            int p = gb[b] + atomicAdd(&lc[b], 1);
            packed[p] = vals[i];
        }
    }
}

// Stage 4: one workgroup per coarse bucket (256 dsts, ~4096 edges).
// Produces exact per-dst CSR (rowStart), degrees (dis), and sortedSrc.

__global__ __launch_bounds__(256) void k_fine(const int* __restrict__ packed,
                                              const int* __restrict__ bbase,
                                              float* __restrict__ dis,
                                              int* __restrict__ rowStart,
                                              int* __restrict__ sortedSrc,
                                              int nE, int n) {
    __shared__ int cnt[256], loc[256], lc[256];
    int t = threadIdx.x;
    int b = blockIdx.x;
    int lo = bbase[b], hi = bbase[b + 1];
    cnt[t] = 0; lc[t] = 0;
    __syncthreads();
    for (int k = lo + t; k < hi; k += 256)
        atomicAdd(&cnt[packed[k] & 255], 1);
    __syncthreads();

    int c = cnt[t];
    int node = (b << 8) + t;
    dis[node] = rsqrtf((float)c + 1.0f);

    loc[t] = c;
    __syncthreads();
    #pragma unroll
    for (int off = 1; off < 256; off <<= 1) {
        int u = (t >= off) ? loc[t - off] : 0;
        __syncthreads();
        loc[t] += u;
        __syncthreads();
    }
    int excl = loc[t] - c;
    rowStart[node] = lo + excl;
    if (b == 0 && t == 0) rowStart[n] = nE;
    __syncthreads();
    loc[t] = excl;
    __syncthreads();

    for (int k = lo + t; k < hi; k += 256) {
        int v = packed[k];
        int dl = v & 255;
        int p = loc[dl] + atomicAdd(&lc[dl], 1);
        sortedSrc[lo + p] = v >> 8;          // src (fits in 16 bits, N=65536)
    }
}

// ================= GEMM: HS = (X @ W) * dis[row] =================

__global__ __launch_bounds__(256) void k_gemm64s(const float* __restrict__ X,
                                                 const float* __restrict__ W,
                                                 const float* __restrict__ dis,
                                                 float* __restrict__ H) {
    __shared__ float Ws[64 * 64];     // [k][f]
    __shared__ float XsT[64 * 68];    // [k][r]

    const int tid  = threadIdx.x;
    const int row0 = blockIdx.x * 64;

    for (int i = tid; i < 4096; i += 256) Ws[i] = W[i];
    for (int i = tid; i < 4096; i += 256) {
        int r = i >> 6, k = i & 63;
        XsT[k * 68 + r] = X[(row0 + r) * FDIM + k];
    }
    __syncthreads();

    const int tx = tid & 15;   // feature quad
    const int ty = tid >> 4;   // row quad

    float4 acc0 = {0,0,0,0}, acc1 = {0,0,0,0}, acc2 = {0,0,0,0}, acc3 = {0,0,0,0};

    #pragma unroll
    for (int k = 0; k < 64; ++k) {
        float4 wv = *(const float4*)&Ws[k * 64 + tx * 4];
        float4 xv = *(const float4*)&XsT[k * 68 + ty * 4];
        acc0.x = fmaf(xv.x, wv.x, acc0.x); acc0.y = fmaf(xv.x, wv.y, acc0.y);
        acc0.z = fmaf(xv.x, wv.z, acc0.z); acc0.w = fmaf(xv.x, wv.w, acc0.w);
        acc1.x = fmaf(xv.y, wv.x, acc1.x); acc1.y = fmaf(xv.y, wv.y, acc1.y);
        acc1.z = fmaf(xv.y, wv.z, acc1.z); acc1.w = fmaf(xv.y, wv.w, acc1.w);
        acc2.x = fmaf(xv.z, wv.x, acc2.x); acc2.y = fmaf(xv.z, wv.y, acc2.y);
        acc2.z = fmaf(xv.z, wv.z, acc2.z); acc2.w = fmaf(xv.z, wv.w, acc2.w);
        acc3.x = fmaf(xv.w, wv.x, acc3.x); acc3.y = fmaf(xv.w, wv.y, acc3.y);
        acc3.z = fmaf(xv.w, wv.z, acc3.z); acc3.w = fmaf(xv.w, wv.w, acc3.w);
    }

    float d0 = dis[row0 + ty * 4 + 0];
    float d1 = dis[row0 + ty * 4 + 1];
    float d2 = dis[row0 + ty * 4 + 2];
    float d3 = dis[row0 + ty * 4 + 3];
    acc0.x *= d0; acc0.y *= d0; acc0.z *= d0; acc0.w *= d0;
    acc1.x *= d1; acc1.y *= d1; acc1.z *= d1; acc1.w *= d1;
    acc2.x *= d2; acc2.y *= d2; acc2.z *= d2; acc2.w *= d2;
    acc3.x *= d3; acc3.y *= d3; acc3.z *= d3; acc3.w *= d3;

    float4* H4 = (float4*)H;
    H4[(row0 + ty * 4 + 0) * 16 + tx] = acc0;
    H4[(row0 + ty * 4 + 1) * 16 + tx] = acc1;
    H4[(row0 + ty * 4 + 2) * 16 + tx] = acc2;
    H4[(row0 + ty * 4 + 3) * 16 + tx] = acc3;
}

// ===== aggregation: out = relu(dis[d]*(sum_{s in N(d)} HS[s] + HS[d]) + b) =====

__global__ __launch_bounds__(256) void k_agg(const float* __restrict__ HS,
                                             const float* __restrict__ dis,
                                             const int* __restrict__ rowStart,
                                             const int* __restrict__ esrc,
                                             const float* __restrict__ bias,
                                             float* __restrict__ out) {
    const int lane = threadIdx.x & 63;
    const int row  = blockIdx.x * 4 + (threadIdx.x >> 6);
    const int fq   = lane & 15;
    const int eq   = lane >> 4;

    const int start = rowStart[row];
    const int end   = rowStart[row + 1];

    const float4* H4 = (const float4*)HS;
    float4 acc = {0.f, 0.f, 0.f, 0.f};

    for (int k = start + eq; k < end; k += 4) {
        int s = esrc[k];
        float4 v = H4[s * 16 + fq];
        acc.x += v.x; acc.y += v.y; acc.z += v.z; acc.w += v.w;
    }

    acc.x += __shfl_xor(acc.x, 16, 64); acc.y += __shfl_xor(acc.y, 16, 64);
    acc.z += __shfl_xor(acc.z, 16, 64); acc.w += __shfl_xor(acc.w, 16, 64);
    acc.x += __shfl_xor(acc.x, 32, 64); acc.y += __shfl_xor(acc.y, 32, 64);
    acc.z += __shfl_xor(acc.z, 32, 64); acc.w += __shfl_xor(acc.w, 32, 64);

    float4 self = H4[row * 16 + fq];
    float  ds   = dis[row];
    float4 bb   = ((const float4*)bias)[fq];

    float4 r;
    r.x = fmaxf(fmaf(acc.x + self.x, ds, bb.x), 0.f);
    r.y = fmaxf(fmaf(acc.y + self.y, ds, bb.y), 0.f);
    r.z = fmaxf(fmaf(acc.z + self.z, ds, bb.z), 0.f);
    r.w = fmaxf(fmaf(acc.w + self.w, ds, bb.w), 0.f);

    if (eq == 0) ((float4*)out)[row * 16 + fq] = r;
}

// ================= launch =================

extern "C" void kernel_launch(void* const* d_in, const int* in_sizes, int n_in,
                              void* d_out, int out_size, void* d_ws, size_t ws_size,
                              hipStream_t stream) {
    const float* x  = (const float*)d_in[0];
    const int*   ei = (const int*)d_in[1];
    const float* W1 = (const float*)d_in[2];
    const float* b1 = (const float*)d_in[3];
    const float* W2 = (const float*)d_in[4];
    const float* b2 = (const float*)d_in[5];

    const int N = in_sizes[0] / FDIM;    // 65536
    const int E = in_sizes[1] / 2;       // 1048576

    char* ws = (char*)d_ws;
    float* dis       = (float*)(ws);                 // 256 KB
    int*   rowStart  = (int*)  (ws + 262144);        // (N+1)*4
    int*   hist      = (int*)  (ws + 524544);        // 256 ints
    int*   bbase     = (int*)  (ws + 525568);        // 257 ints
    int*   cursor    = (int*)  (ws + 526848);        // 256 ints
    int*   sortedSrc = (int*)  (ws + 528384);        // E ints (4 MB)
    // packed shares storage with A: packed is dead before the first GEMM writes A.
    int*   packed    = (int*)  (ws + 528384 + 4194304);
    float* A         = (float*)(ws + 528384 + 4194304);   // N*64 floats (16 MB)
    float* B         = (float*)d_out;

    const int histBlocks = (E + 8191) / 8192;        // 128

    // ---- CSR build + degrees (shared by both layers) ----
    hipMemsetAsync(hist, 0, 256 * sizeof(int), stream);
    k_hist   <<<histBlocks, 256, 0, stream>>>(ei, hist, E);
    k_scan256<<<1, 256, 0, stream>>>(hist, bbase, cursor, E);
    k_coarse <<<histBlocks, 256, 0, stream>>>(ei, cursor, packed, E);
    k_fine   <<<256, 256, 0, stream>>>(packed, bbase, dis, rowStart, sortedSrc, E, N);

    // ---- layer 1 ----
    k_gemm64s<<<N / 64, 256, 0, stream>>>(x, W1, dis, A);
    k_agg    <<<N / 4, 256, 0, stream>>>(A, dis, rowStart, sortedSrc, b1, B);

    // ---- layer 2 ----
    k_gemm64s<<<N / 64, 256, 0, stream>>>(B, W2, dis, A);
    k_agg    <<<N / 4, 256, 0, stream>>>(A, dis, rowStart, sortedSrc, b2, (float*)d_out);
}